// Round 16
// baseline (89.764 us; speedup 1.0000x reference)
//
#include <hip/hip_runtime.h>
#include <hip/hip_bf16.h>

// SpectralConv1d: out = irfft( pad( einsum('bjix,iox->bjox', rfft(x)[..:64], wr+i*wi) ), n=2048 )
// FUSED GEMM1+MIX (DFT + complex channel mix, KS=1/BM=64/512thr: block bj holds full
// A[bj,:,:] slab -> LDS -> in-block mix -> pre-swizzled Bx; no P intermediate)
// -> GEMM2 (inverse DFT; BM=128 x BN=64, pure-DMA staging from pre-swizzled images).

typedef __bf16 bf16x8 __attribute__((ext_vector_type(8)));
typedef float  f32x4  __attribute__((ext_vector_type(4)));

#define SEQ 2048
#define NM2 128   // 2*MODES (Re | Im planes)

__device__ __forceinline__ unsigned int rnbf(float f) {
  unsigned int u = __builtin_bit_cast(unsigned int, f);
  return (u + 0x7fffu + ((u >> 16) & 1u)) >> 16;  // round-to-nearest-even bf16
}
__device__ __forceinline__ unsigned int pack2(float a, float b) {
  return rnbf(a) | (rnbf(b) << 16);
}

typedef const __attribute__((address_space(1))) unsigned int gu32;
typedef __attribute__((address_space(3))) unsigned int lu32;

// ---------------- K0: trig tables (hw v_sin/v_cos, revolution args) ----------------
// t1sw: 32 tiles of 16 KB; tile kt = PRE-SWIZZLED LDS image of T1T[c][kt*64..+63]:
//       byte ((c*128 + part*16) ^ ((c&7)<<4)) + 2*e ; c<64: cos(2pi k n/N); c>=64: -sin
// t2sw: 16 tiles of 32 KB; tile nb = PRE-SWIZZLED image of T2 rows [nb*128, +128):
//       half h (Re|Im) at tile*32768 + h*16384; within half (row stride 128 B):
//       byte rl*128 + ((((k&63)>>3)*16) ^ ((rl&7)<<4)) + 2*(k&7), rl = n&127.
__global__ __launch_bounds__(256) void k_tables(unsigned short* __restrict__ t1sw,
                                                unsigned short* __restrict__ t2sw) {
  int idx = blockIdx.x * 256 + threadIdx.x;   // 0..131071
  int k = idx >> 11;                          // 0..63
  int n = idx & 2047;
  float rev = (float)((k * n) & 2047) * (1.0f / 2048.0f);   // phase in revolutions
  float s, co;
  asm("v_sin_f32 %0, %1" : "=v"(s)  : "v"(rev));
  asm("v_cos_f32 %0, %1" : "=v"(co) : "v"(rev));
  float ck = (k == 0 ? 1.0f : 2.0f) * (1.0f / 2048.0f);
  {
    int kt = n >> 6, part = (n >> 3) & 7, e = n & 7;
    unsigned base = (unsigned)kt * 16384u + 2u * (unsigned)e;
    unsigned offc = base + (((unsigned)(k * 128 + part * 16)) ^ (((unsigned)k & 7u) << 4));
    int c2 = k + 64;
    unsigned offs = base + (((unsigned)(c2 * 128 + part * 16)) ^ (((unsigned)c2 & 7u) << 4));
    *(unsigned short*)((char*)t1sw + offc) = (unsigned short)rnbf(co);
    *(unsigned short*)((char*)t1sw + offs) = (unsigned short)rnbf(-s);
  }
  {
    int tile = n >> 7, rl = n & 127;
    unsigned rowbase = (unsigned)tile * 32768u + (unsigned)rl * 128u;
    unsigned kpart = ((((unsigned)(k >> 3)) * 16u) ^ (((unsigned)rl & 7u) << 4)) + 2u * ((unsigned)k & 7u);
    *(unsigned short*)((char*)t2sw + rowbase + kpart)          = (unsigned short)rnbf(ck * co);
    *(unsigned short*)((char*)t2sw + rowbase + 16384u + kpart) = (unsigned short)rnbf(-ck * s);
  }
}

// ---------------- K1: FUSED  A[bj] = x[bj rows] @ T1 ; Bx[bj] = mix(A[bj], w) ----------
// Block bj (grid 256, 512 threads = 8 waves in 4x2). BK=64, full K (32 iters), 64 KB LDS
// dbuf (x fp32 16K x2 @0; t1 bf16 16K x2 @32K), all-DMA staging, issue-ahead schedule.
// Swapped MFMA (D^T): lane holds (row=i, 4 consecutive cols). Epilogue: A-slab -> LDS
// fp32 [64][136], then complex mix (o=tid>>3, k 8-wide) -> pre-swizzled Bx tile images.
__global__ __launch_bounds__(512) void k_gemm1f(const float* __restrict__ x,
                                                const unsigned short* __restrict__ t1sw,
                                                const float* __restrict__ wre,
                                                const float* __restrict__ wim,
                                                char* __restrict__ Bxsw) {
  __shared__ int4 lds4[65536 / 16];
  char* lds = (char*)lds4;
  const int tid = threadIdx.x, wave = tid >> 6, lane = tid & 63;
  const int bj = blockIdx.x;
  const int r0 = bj * 64;

  // x DMA sites p=0,1: row = p*32 + wave*4 + (lane>>4); 16B unit (lane&15)^(row&7)
  const float* xsrc[2];
#pragma unroll
  for (int p = 0; p < 2; ++p) {
    const int row = p * 32 + wave * 4 + (lane >> 4);
    const int u = (lane & 15) ^ (row & 7);
    xsrc[p] = x + (size_t)(r0 + row) * SEQ + u * 4;
  }

  f32x4 acc[4] = {};

#define XSTAGE(it, buf)                                                               \
  {                                                                                   \
    _Pragma("unroll")                                                                 \
    for (int p = 0; p < 2; ++p)                                                       \
      __builtin_amdgcn_global_load_lds((gu32*)(xsrc[p] + (it) * 64),                  \
          (lu32*)(lds + (buf) * 16384 + p * 8192 + wave * 1024), 16, 0, 0);           \
  }
#define TSTAGE(it, buf)                                                               \
  {                                                                                   \
    const char* tg_ = (const char*)t1sw + (size_t)(it) * 16384;                       \
    _Pragma("unroll")                                                                 \
    for (int q = 0; q < 2; ++q)                                                       \
      __builtin_amdgcn_global_load_lds((gu32*)(tg_ + (q * 512 + tid) * 16),           \
          (lu32*)(lds + 32768 + (buf) * 16384 + q * 8192 + wave * 1024), 16, 0, 0);   \
  }

  // ---- prologue: stage tile 0 ----
  XSTAGE(0, 0);
  TSTAGE(0, 0);
  asm volatile("s_waitcnt vmcnt(0)" ::: "memory");
  __builtin_amdgcn_s_barrier();

  const int wr4 = wave >> 1, wc = wave & 1;
  const int a = wr4 * 16 + (lane & 15);        // i-row of the A slab
  const unsigned xra = (unsigned)(a & 7) << 4;
  const int kg = lane >> 4;

  for (int it = 0; it < 32; ++it) {
    const int cur = it & 1, nxt = cur ^ 1;
    const int xoff = cur * 16384;
    const int toff = 32768 + cur * 16384;
    if (it < 31) {
      XSTAGE(it + 1, nxt);
      TSTAGE(it + 1, nxt);
    }
#pragma unroll
    for (int kss = 0; kss < 2; ++kss) {
      const unsigned byte0 = (unsigned)(a * 256 + kss * 128 + kg * 32);
      const f32x4 lo = *(const f32x4*)(lds + xoff + (byte0 ^ xra));
      const f32x4 hi = *(const f32x4*)(lds + xoff + ((byte0 + 16) ^ xra));
      unsigned c0, c1, c2, c3;
      asm("v_cvt_pk_bf16_f32 %0, %1, %2" : "=v"(c0) : "v"(lo[0]), "v"(lo[1]));
      asm("v_cvt_pk_bf16_f32 %0, %1, %2" : "=v"(c1) : "v"(lo[2]), "v"(lo[3]));
      asm("v_cvt_pk_bf16_f32 %0, %1, %2" : "=v"(c2) : "v"(hi[0]), "v"(hi[1]));
      asm("v_cvt_pk_bf16_f32 %0, %1, %2" : "=v"(c3) : "v"(hi[2]), "v"(hi[3]));
      uint4 pk; pk.x = c0; pk.y = c1; pk.z = c2; pk.w = c3;
      const bf16x8 av = __builtin_bit_cast(bf16x8, pk);
#pragma unroll
      for (int t = 0; t < 4; ++t) {
        const int col = wc * 64 + t * 16 + (lane & 15);
        const bf16x8 bv = *(const bf16x8*)(lds + toff +
            ((col * 128 + kss * 64 + kg * 16) ^ ((unsigned)(col & 7) << 4)));
        acc[t] = __builtin_amdgcn_mfma_f32_16x16x32_bf16(bv, av, acc[t], 0, 0, 0);  // D^T
      }
    }
    asm volatile("s_waitcnt vmcnt(0)" ::: "memory");
    __builtin_amdgcn_s_barrier();
  }
#undef XSTAGE
#undef TSTAGE

  // ---- epilogue 1: A slab -> LDS fp32 [64][136] (pad breaks bank conflicts) ----
  float* sA = (float*)lds;
#pragma unroll
  for (int t = 0; t < 4; ++t) {
    const int col0 = wc * 64 + t * 16 + kg * 4;   // lane holds 4 consecutive cols (D^T)
    *(f32x4*)(sA + a * 136 + col0) = acc[t];
  }
  __syncthreads();

  // ---- epilogue 2: complex mix. thread: o = tid>>3 (0..63), k-octet kb = (tid&7)*8 ----
  const int o = tid >> 3;
  const int kb = (tid & 7) * 8;
  f32x4 accr0 = {}, accr1 = {}, acci0 = {}, acci1 = {};
  for (int i = 0; i < 64; ++i) {
    const float* wp = wre + (size_t)(i * 64 + o) * 64 + kb;
    const float* wq = wim + (size_t)(i * 64 + o) * 64 + kb;
    const f32x4 w0 = *(const f32x4*)(wp),     w1 = *(const f32x4*)(wp + 4);
    const f32x4 v0 = *(const f32x4*)(wq),     v1 = *(const f32x4*)(wq + 4);
    const float* ap = sA + i * 136 + kb;
    const f32x4 ar0 = *(const f32x4*)(ap),      ar1 = *(const f32x4*)(ap + 4);
    const f32x4 ai0 = *(const f32x4*)(ap + 64), ai1 = *(const f32x4*)(ap + 68);
#pragma unroll
    for (int kk = 0; kk < 4; ++kk) {
      accr0[kk] += ar0[kk] * w0[kk] - ai0[kk] * v0[kk];
      accr1[kk] += ar1[kk] * w1[kk] - ai1[kk] * v1[kk];
      acci0[kk] += ar0[kk] * v0[kk] + ai0[kk] * w0[kk];
      acci1[kk] += ar1[kk] * v1[kk] + ai1[kk] * w1[kk];
    }
  }
  // write Bx pre-swizzled: r = bj*64+o; this thread's 8 k live in ONE 16B span per half
  const int r = bj * 64 + o;
  const int tile = r >> 7, rl = r & 127;
  char* bb = Bxsw + (size_t)tile * 32768 + (size_t)rl * 128;
  const unsigned kp0 = (((unsigned)(kb >> 3)) * 16u) ^ (((unsigned)rl & 7u) << 4);
  uint4 vr; vr.x = pack2(accr0[0], accr0[1]); vr.y = pack2(accr0[2], accr0[3]);
            vr.z = pack2(accr1[0], accr1[1]); vr.w = pack2(accr1[2], accr1[3]);
  uint4 vi; vi.x = pack2(acci0[0], acci0[1]); vi.y = pack2(acci0[2], acci0[3]);
            vi.z = pack2(acci1[0], acci1[1]); vi.w = pack2(acci1[2], acci1[3]);
  *(uint4*)(bb + kp0)         = vr;   // Re half
  *(uint4*)(bb + 16384 + kp0) = vi;   // Im half
}

// ---------------- K3: GEMM2  out[16384][2048] = Bx[16384][128] @ T2 ----------------
// BM=128, BN=64, K=128. LDS 48 KB -> 3 blocks/CU. Pure-DMA staging from PRE-SWIZZLED
// images: full Bx mb-tile (32 KB) + the 64-row slice of the t2 nb-tile (16 KB).
// Half-pipelined: issue 12 gll -> vmcnt(6) -> barrier -> h0 -> vmcnt(0) -> barrier -> h1.
// Stores: per row 4 back-to-back 64B stores = contiguous 256B. Grid 4096, XCD swizzle.
__global__ __launch_bounds__(256) void k_gemm2(const char* __restrict__ Bxsw,
                                               const char* __restrict__ t2sw,
                                               float* __restrict__ out) {
  __shared__ int4 lds4[49152 / 16];   // [0,16K) Bx-h0 | [16K,32K) Bx-h1 | [32K,48K) t2 h0|h1
  char* lds = (char*)lds4;
  const int tid = threadIdx.x, wave = tid >> 6, lane = tid & 63;
  const int swz = (blockIdx.x & 7) * 512 + (blockIdx.x >> 3);   // XCD-contiguous (4096%8==0)
  const int mb = swz >> 5, nb64 = swz & 31;
  const int r0 = mb * 128, n0 = nb64 * 64;
  const char* bsrc = Bxsw + (size_t)mb * 32768;
  const char* tsrc = t2sw + (size_t)(nb64 >> 1) * 32768 + (size_t)(nb64 & 1) * 8192;  // row slice
#pragma unroll
  for (int i = 0; i < 4; ++i)
    __builtin_amdgcn_global_load_lds((gu32*)(bsrc + i * 4096 + tid * 16),
                                     (lu32*)(lds + i * 4096 + wave * 1024), 16, 0, 0);
#pragma unroll
  for (int i = 0; i < 2; ++i)
    __builtin_amdgcn_global_load_lds((gu32*)(tsrc + i * 4096 + tid * 16),
                                     (lu32*)(lds + 32768 + i * 4096 + wave * 1024), 16, 0, 0);
#pragma unroll
  for (int i = 0; i < 4; ++i)
    __builtin_amdgcn_global_load_lds((gu32*)(bsrc + 16384 + i * 4096 + tid * 16),
                                     (lu32*)(lds + 16384 + i * 4096 + wave * 1024), 16, 0, 0);
#pragma unroll
  for (int i = 0; i < 2; ++i)
    __builtin_amdgcn_global_load_lds((gu32*)(tsrc + 16384 + i * 4096 + tid * 16),
                                     (lu32*)(lds + 40960 + i * 4096 + wave * 1024), 16, 0, 0);
  asm volatile("s_waitcnt vmcnt(6)" ::: "memory");   // h0 of both operands landed
  __builtin_amdgcn_s_barrier();

  f32x4 acc[2][4] = {};
  const int rowA0 = wave * 32 + (lane & 15);
  const int rowA1 = rowA0 + 16;
  const unsigned xa0 = (unsigned)(rowA0 & 7) << 4;
  const unsigned xa1 = (unsigned)(rowA1 & 7) << 4;

#pragma unroll
  for (int half = 0; half < 2; ++half) {
    if (half == 1) {
      asm volatile("s_waitcnt vmcnt(0)" ::: "memory");
      __builtin_amdgcn_s_barrier();
    }
    const int ab = half * 16384;           // Bx half base
    const int bb = 32768 + half * 8192;    // t2 half base (64 rows x 128 B)
#pragma unroll
    for (int kq = 0; kq < 2; ++kq) {       // 32 k = 64 B per 128-B row
      const unsigned offh = (unsigned)(kq * 64 + (lane >> 4) * 16);
      const bf16x8 a0 = *(const bf16x8*)(lds + ab + rowA0 * 128 + (offh ^ xa0));
      const bf16x8 a1 = *(const bf16x8*)(lds + ab + rowA1 * 128 + (offh ^ xa1));
#pragma unroll
      for (int t = 0; t < 4; ++t) {
        const int rn = t * 16 + (lane & 15);
        const bf16x8 bv = *(const bf16x8*)(lds + bb + rn * 128 + (offh ^ ((unsigned)(rn & 7) << 4)));
        acc[0][t] = __builtin_amdgcn_mfma_f32_16x16x32_bf16(a0, bv, acc[0][t], 0, 0, 0);
        acc[1][t] = __builtin_amdgcn_mfma_f32_16x16x32_bf16(a1, bv, acc[1][t], 0, 0, 0);
      }
    }
  }
#pragma unroll
  for (int m = 0; m < 2; ++m) {
#pragma unroll
    for (int j = 0; j < 4; ++j) {
      const int row = r0 + wave * 32 + m * 16 + (lane >> 4) * 4 + j;
#pragma unroll
      for (int t = 0; t < 4; ++t) {
        const int col = n0 + t * 16 + (lane & 15);
        out[(size_t)row * SEQ + col] = acc[m][t][j];
      }
    }
  }
}

extern "C" void kernel_launch(void* const* d_in, const int* in_sizes, int n_in,
                              void* d_out, int out_size, void* d_ws, size_t ws_size,
                              hipStream_t stream) {
  const float* x  = (const float*)d_in[0];
  const float* wr = (const float*)d_in[1];
  const float* wi = (const float*)d_in[2];
  float* out = (float*)d_out;
  char* ws = (char*)d_ws;
  // ws layout: t1sw 512K | t2sw 512K | Bxsw 4M   (total ~5 MB; no P intermediate)
  unsigned short* t1sw = (unsigned short*)(ws);
  unsigned short* t2sw = (unsigned short*)(ws + 524288);
  char*           Bxsw = (char*)(ws + 1048576);

  k_tables<<<dim3(512),  dim3(256), 0, stream>>>(t1sw, t2sw);
  k_gemm1f<<<dim3(256),  dim3(512), 0, stream>>>(x, t1sw, wr, wi, Bxsw);
  k_gemm2 <<<dim3(4096), dim3(256), 0, stream>>>(Bxsw, (const char*)t2sw, out);
}